// Round 2
// baseline (257.978 us; speedup 1.0000x reference)
//
#include <hip/hip_runtime.h>

typedef __bf16 bf16;
typedef __attribute__((ext_vector_type(4))) __bf16 bf16x4;
typedef __attribute__((ext_vector_type(8))) __bf16 bf16x8;
typedef __attribute__((ext_vector_type(4))) float f32x4;

#define B_ 4
#define S_ 2048
#define H_ 16
#define D_ 64
#define E_ 1024

__device__ __forceinline__ int imin(int a, int b) { return a < b ? a : b; }
__device__ __forceinline__ int imax(int a, int b) { return a > b ? a : b; }

__device__ __forceinline__ void gload_lds16(const void* g, void* l) {
  __builtin_amdgcn_global_load_lds(
      (const __attribute__((address_space(1))) void*)g,
      (__attribute__((address_space(3))) void*)l, 16, 0, 0);
}

// ---------------- f32 -> bf16 convert ----------------
__global__ __launch_bounds__(256) void f32_to_bf16_kernel(
    const float* __restrict__ in, bf16* __restrict__ out, int n) {
  int i = (blockIdx.x * 256 + threadIdx.x) * 4;
  const int stride = gridDim.x * 256 * 4;
  for (; i < n; i += stride) {
    float4 v = *(const float4*)(in + i);
    bf16x4 o;
    o[0] = (bf16)v.x; o[1] = (bf16)v.y; o[2] = (bf16)v.z; o[3] = (bf16)v.w;
    *(bf16x4*)(out + i) = o;
  }
}

// ---------------- NT bf16 GEMM: C[m,n] = sum_k A[m,k]*B[n,k] ----------------
// mode 0: epilogue scatters q (scaled 0.125), k -> [B,H,S,D]; v -> vt [B,H,D,S]
// mode 1: epilogue writes f32 C row-major [M,N]
__global__ __launch_bounds__(256) void gemm_nt(
    const bf16* __restrict__ A, const bf16* __restrict__ Bm,
    int M, int N, int K, int mode,
    bf16* __restrict__ qd, bf16* __restrict__ kd, bf16* __restrict__ vtd,
    float* __restrict__ outf) {
  __shared__ __align__(16) bf16 As[128 * 64];
  __shared__ __align__(16) bf16 Bs[128 * 64];
  const int tid = threadIdx.x;
  const int wave = tid >> 6, lane = tid & 63;
  const int l15 = lane & 15, l4 = lane >> 4;
  const int tn = blockIdx.x, tm = blockIdx.y;
  const int wm = (wave >> 1) * 64, wn = (wave & 1) * 64;

  f32x4 acc[4][4];
#pragma unroll
  for (int i = 0; i < 4; ++i)
#pragma unroll
    for (int j = 0; j < 4; ++j)
#pragma unroll
      for (int r = 0; r < 4; ++r) acc[i][j][r] = 0.f;

  const bf16* Abase = A + (size_t)tm * 128 * K;
  const bf16* Bbase = Bm + (size_t)tn * 128 * K;

  for (int k0 = 0; k0 < K; k0 += 64) {
#pragma unroll
    for (int it = 0; it < 4; ++it) {
      const int gidx = it * 256 + tid;
      const int row = gidx >> 3, c = gidx & 7;
      const int csw = c ^ (row & 7);  // pre-swizzled global source (m201 pattern)
      gload_lds16(Abase + (size_t)row * K + k0 + csw * 8,
                  As + (size_t)(it * 256 + wave * 64) * 8);
      gload_lds16(Bbase + (size_t)row * K + k0 + csw * 8,
                  Bs + (size_t)(it * 256 + wave * 64) * 8);
    }
    __syncthreads();
#pragma unroll
    for (int kc = 0; kc < 2; ++kc) {
      bf16x8 af[4], bfr[4];
#pragma unroll
      for (int i = 0; i < 4; ++i) {
        const int ra = wm + i * 16 + l15;
        af[i] = *(const bf16x8*)(As + ra * 64 + (((kc * 4 + l4) ^ (ra & 7)) * 8));
        const int rb = wn + i * 16 + l15;
        bfr[i] = *(const bf16x8*)(Bs + rb * 64 + (((kc * 4 + l4) ^ (rb & 7)) * 8));
      }
#pragma unroll
      for (int i = 0; i < 4; ++i)
#pragma unroll
        for (int j = 0; j < 4; ++j)
          acc[i][j] = __builtin_amdgcn_mfma_f32_16x16x32_bf16(af[i], bfr[j],
                                                              acc[i][j], 0, 0, 0);
    }
    __syncthreads();
  }

  if (mode == 0) {
#pragma unroll
    for (int i = 0; i < 4; ++i) {
      const int m0 = tm * 128 + wm + i * 16 + l4 * 4;
      const int b = m0 >> 11, s = m0 & (S_ - 1);
#pragma unroll
      for (int j = 0; j < 4; ++j) {
        const int n = tn * 128 + wn + j * 16 + l15;
        const int which = n >> 10;
        const int hn = n & 1023;
        const int h = hn >> 6, d = hn & 63;
        const f32x4 a = acc[i][j];
        if (which == 0) {
#pragma unroll
          for (int r = 0; r < 4; ++r)
            qd[((size_t)(b * H_ + h) * S_ + (s + r)) * D_ + d] =
                (bf16)(a[r] * 0.125f);
        } else if (which == 1) {
#pragma unroll
          for (int r = 0; r < 4; ++r)
            kd[((size_t)(b * H_ + h) * S_ + (s + r)) * D_ + d] = (bf16)a[r];
        } else {
          bf16x4 pv;
#pragma unroll
          for (int r = 0; r < 4; ++r) pv[r] = (bf16)a[r];
          *(bf16x4*)(vtd + ((size_t)(b * H_ + h) * D_ + d) * S_ + s) = pv;
        }
      }
    }
  } else {
#pragma unroll
    for (int i = 0; i < 4; ++i) {
      const int m0 = tm * 128 + wm + i * 16 + l4 * 4;
#pragma unroll
      for (int j = 0; j < 4; ++j) {
        const int n = tn * 128 + wn + j * 16 + l15;
#pragma unroll
        for (int r = 0; r < 4; ++r) outf[(size_t)(m0 + r) * N + n] = acc[i][j][r];
      }
    }
  }
}

// ---------------- mean of v over all S (for fully-masked rows) ----------------
__global__ __launch_bounds__(256) void meanv_kernel(const bf16* __restrict__ vt,
                                                    float* __restrict__ meanv) {
  __shared__ float part[256];
  const int bh = blockIdx.x;
  const int tid = threadIdx.x;
  const int d = tid & 63, seg = tid >> 6;
  const bf16* row = vt + ((size_t)bh * D_ + d) * S_ + seg * 512;
  float s = 0.f;
  for (int i = 0; i < 512; i += 8) {
    bf16x8 v = *(const bf16x8*)(row + i);
#pragma unroll
    for (int j = 0; j < 8; ++j) s += (float)v[j];
  }
  part[tid] = s;
  __syncthreads();
  if (tid < 64) {
    float t = part[tid] + part[64 + tid] + part[128 + tid] + part[192 + tid];
    meanv[(size_t)bh * D_ + tid] = t * (1.0f / (float)S_);
  }
}

// ---------------- flash attention, 32-key tiles, 16 q-rows per wave ----------------
__global__ __launch_bounds__(256) void attn_kernel(
    const bf16* __restrict__ q, const bf16* __restrict__ k,
    const bf16* __restrict__ vt, const float* __restrict__ meanv,
    const int* __restrict__ seq_lengths, const int* __restrict__ wlp,
    const int* __restrict__ wrp, bf16* __restrict__ attn_out) {
  __shared__ __align__(16) bf16 Pl[4][16 * 40];  // padded stride 40 elems
  const int tid = threadIdx.x, wave = tid >> 6, lane = tid & 63;
  const int l15 = lane & 15, l4 = lane >> 4;
  const int bid = blockIdx.x;
  const int bh = bid >> 5;   // 32 blocks of 64 rows per (b,h)
  const int g = bid & 31;
  const int b = bh >> 4, h = bh & 15;
  const int q0b = g * 64;
  const int q0w = q0b + wave * 16;
  const int seq_len = seq_lengths[b];
  const int wl = wlp[0], wr = wrp[0];

  const bf16* qbase = q + (size_t)bh * S_ * D_;
  const bf16* kbase = k + (size_t)bh * S_ * D_;
  const bf16* vtb = vt + (size_t)bh * D_ * S_;

  bf16x8 qa[2];
#pragma unroll
  for (int kc = 0; kc < 2; ++kc)
    qa[kc] = *(const bf16x8*)(qbase + (size_t)(q0w + l15) * D_ + kc * 32 + l4 * 8);

  const int hi = (wr >= 0) ? imin(q0b + 63 + wr, S_ - 1) : (S_ - 1);
  const int kv_end = imin(hi + 1, seq_len);
  const int lo = (wl >= 0) ? imax(0, q0b - wl) : 0;
  const int kv_begin = lo & ~31;

  f32x4 o[4];
#pragma unroll
  for (int df = 0; df < 4; ++df)
#pragma unroll
    for (int r = 0; r < 4; ++r) o[df][r] = 0.f;
  float mrun[4], lrun[4];
#pragma unroll
  for (int r = 0; r < 4; ++r) { mrun[r] = -1e30f; lrun[r] = 0.f; }

  for (int kt = kv_begin; kt < kv_end; kt += 32) {
    // ---- QK^T (16 q-rows x 32 keys) ----
    f32x4 sf[2];
#pragma unroll
    for (int nf = 0; nf < 2; ++nf)
#pragma unroll
      for (int r = 0; r < 4; ++r) sf[nf][r] = 0.f;
#pragma unroll
    for (int nf = 0; nf < 2; ++nf)
#pragma unroll
      for (int kc = 0; kc < 2; ++kc) {
        bf16x8 kb = *(const bf16x8*)(kbase + (size_t)(kt + nf * 16 + l15) * D_ +
                                     kc * 32 + l4 * 8);
        sf[nf] = __builtin_amdgcn_mfma_f32_16x16x32_bf16(qa[kc], kb, sf[nf], 0, 0, 0);
      }
    // ---- mask + online softmax ----
    float p[2][4], tmax[4];
#pragma unroll
    for (int r = 0; r < 4; ++r) {
      const int qrow = q0w + l4 * 4 + r;
      float mx = -1e30f;
#pragma unroll
      for (int nf = 0; nf < 2; ++nf) {
        const int key = kt + nf * 16 + l15;
        bool valid = (key < seq_len);
        if (wr >= 0) valid = valid && (key <= qrow + wr);
        if (wl >= 0) valid = valid && (key >= qrow - wl);
        const float sv = valid ? sf[nf][r] : -1e30f;
        p[nf][r] = sv;
        mx = fmaxf(mx, sv);
      }
      tmax[r] = mx;
    }
#pragma unroll
    for (int dd = 1; dd < 16; dd <<= 1)
#pragma unroll
      for (int r = 0; r < 4; ++r)
        tmax[r] = fmaxf(tmax[r], __shfl_xor(tmax[r], dd, 64));
    float corr[4], lsum[4];
#pragma unroll
    for (int r = 0; r < 4; ++r) {
      const float mnew = fmaxf(mrun[r], tmax[r]);
      corr[r] = __expf(mrun[r] - mnew);
      mrun[r] = mnew;
      float s0 = 0.f;
#pragma unroll
      for (int nf = 0; nf < 2; ++nf) {
        const float pe = (p[nf][r] <= -1e29f) ? 0.f : __expf(p[nf][r] - mnew);
        p[nf][r] = pe;
        s0 += pe;
      }
      lsum[r] = s0;
    }
#pragma unroll
    for (int dd = 1; dd < 16; dd <<= 1)
#pragma unroll
      for (int r = 0; r < 4; ++r) lsum[r] += __shfl_xor(lsum[r], dd, 64);
#pragma unroll
    for (int r = 0; r < 4; ++r) {
      lrun[r] = lrun[r] * corr[r] + lsum[r];
#pragma unroll
      for (int df = 0; df < 4; ++df) o[df][r] *= corr[r];
    }
    // ---- P -> LDS transpose -> A-frag ----
    __syncthreads();  // protect Pl from previous iteration's reads
#pragma unroll
    for (int nf = 0; nf < 2; ++nf)
#pragma unroll
      for (int r = 0; r < 4; ++r)
        Pl[wave][(l4 * 4 + r) * 40 + nf * 16 + l15] = (bf16)p[nf][r];
    __syncthreads();
    bf16x8 pa = *(const bf16x8*)(&Pl[wave][l15 * 40 + l4 * 8]);
    // ---- PV ----
#pragma unroll
    for (int df = 0; df < 4; ++df) {
      bf16x8 vb = *(const bf16x8*)(vtb + (size_t)(df * 16 + l15) * S_ + kt + l4 * 8);
      o[df] = __builtin_amdgcn_mfma_f32_16x16x32_bf16(pa, vb, o[df], 0, 0, 0);
    }
  }

  // ---- epilogue: divide by l (or mean_v fallback for fully-masked rows) ----
#pragma unroll
  for (int df = 0; df < 4; ++df) {
    const int d = df * 16 + l15;
#pragma unroll
    for (int r = 0; r < 4; ++r) {
      const int qrow = q0w + l4 * 4 + r;
      float val;
      if (lrun[r] > 0.f)
        val = o[df][r] / lrun[r];
      else
        val = meanv[(size_t)bh * D_ + d];
      attn_out[((size_t)(b * S_ + qrow)) * E_ + h * 64 + d] = (bf16)val;
    }
  }
}

// ---------------- launch ----------------
extern "C" void kernel_launch(void* const* d_in, const int* in_sizes, int n_in,
                              void* d_out, int out_size, void* d_ws, size_t ws_size,
                              hipStream_t stream) {
  const float* x = (const float*)d_in[0];
  const float* Wqkv = (const float*)d_in[1];
  const float* Wout = (const float*)d_in[2];
  const int* seq_lengths = (const int*)d_in[3];
  const int* wl = (const int*)d_in[4];
  const int* wr = (const int*)d_in[5];
  float* out = (float*)d_out;

  char* ws = (char*)d_ws;
  bf16* xb = (bf16*)ws;      ws += (size_t)8192 * 1024 * 2;
  bf16* wqkvb = (bf16*)ws;   ws += (size_t)3072 * 1024 * 2;
  bf16* woutb = (bf16*)ws;   ws += (size_t)1024 * 1024 * 2;
  bf16* qd = (bf16*)ws;      ws += (size_t)B_ * H_ * S_ * D_ * 2;
  bf16* kd = (bf16*)ws;      ws += (size_t)B_ * H_ * S_ * D_ * 2;
  bf16* vtd = (bf16*)ws;     ws += (size_t)B_ * H_ * S_ * D_ * 2;
  bf16* attn = (bf16*)ws;    ws += (size_t)8192 * 1024 * 2;
  float* meanv = (float*)ws; ws += (size_t)B_ * H_ * D_ * 4;

  f32_to_bf16_kernel<<<2048, 256, 0, stream>>>(x, xb, 8192 * 1024);
  f32_to_bf16_kernel<<<1024, 256, 0, stream>>>(Wqkv, wqkvb, 3072 * 1024);
  f32_to_bf16_kernel<<<512, 256, 0, stream>>>(Wout, woutb, 1024 * 1024);

  gemm_nt<<<dim3(24, 64), 256, 0, stream>>>(xb, wqkvb, 8192, 3072, 1024, 0,
                                            qd, kd, vtd, nullptr);
  meanv_kernel<<<64, 256, 0, stream>>>(vtd, meanv);
  attn_kernel<<<2048, 256, 0, stream>>>(qd, kd, vtd, meanv, seq_lengths, wl, wr,
                                        attn);
  gemm_nt<<<dim3(8, 64), 256, 0, stream>>>(attn, woutb, 8192, 1024, 1024, 1,
                                           nullptr, nullptr, nullptr, out);
}

// Round 3
// 194.234 us; speedup vs baseline: 1.3282x; 1.3282x over previous
//
#include <hip/hip_runtime.h>

typedef __bf16 bf16;
typedef __attribute__((ext_vector_type(2))) __bf16 bf16x2;
typedef __attribute__((ext_vector_type(4))) __bf16 bf16x4;
typedef __attribute__((ext_vector_type(8))) __bf16 bf16x8;
typedef __attribute__((ext_vector_type(4))) float f32x4;
typedef __attribute__((ext_vector_type(16))) float f32x16;

#define B_ 4
#define S_ 2048
#define H_ 16
#define D_ 64
#define E_ 1024

__device__ __forceinline__ int imin(int a, int b) { return a < b ? a : b; }
__device__ __forceinline__ int imax(int a, int b) { return a > b ? a : b; }

__device__ __forceinline__ void gload_lds16(const void* g, void* l) {
  __builtin_amdgcn_global_load_lds(
      (const __attribute__((address_space(1))) void*)g,
      (__attribute__((address_space(3))) void*)l, 16, 0, 0);
}

// ---------------- f32 -> bf16 convert (8 elems/thread) ----------------
__global__ __launch_bounds__(256) void f32_to_bf16_kernel(
    const float* __restrict__ in, bf16* __restrict__ out, int n) {
  int i = (blockIdx.x * 256 + threadIdx.x) * 8;
  const int stride = gridDim.x * 256 * 8;
  for (; i < n; i += stride) {
    float4 v0 = *(const float4*)(in + i);
    float4 v1 = *(const float4*)(in + i + 4);
    bf16x8 o;
    o[0] = (bf16)v0.x; o[1] = (bf16)v0.y; o[2] = (bf16)v0.z; o[3] = (bf16)v0.w;
    o[4] = (bf16)v1.x; o[5] = (bf16)v1.y; o[6] = (bf16)v1.z; o[7] = (bf16)v1.w;
    *(bf16x8*)(out + i) = o;
  }
}

// ---------------- NT bf16 GEMM: C[m,n] = sum_k A[m,k]*B[n,k] ----------------
__global__ __launch_bounds__(256) void gemm_nt(
    const bf16* __restrict__ A, const bf16* __restrict__ Bm,
    int M, int N, int K, int mode,
    bf16* __restrict__ qd, bf16* __restrict__ kd, bf16* __restrict__ vtd,
    float* __restrict__ outf) {
  __shared__ __align__(16) bf16 As[128 * 64];
  __shared__ __align__(16) bf16 Bs[128 * 64];
  const int tid = threadIdx.x;
  const int wave = tid >> 6, lane = tid & 63;
  const int l15 = lane & 15, l4 = lane >> 4;
  const int tn = blockIdx.x, tm = blockIdx.y;
  const int wm = (wave >> 1) * 64, wn = (wave & 1) * 64;

  f32x4 acc[4][4];
#pragma unroll
  for (int i = 0; i < 4; ++i)
#pragma unroll
    for (int j = 0; j < 4; ++j)
#pragma unroll
      for (int r = 0; r < 4; ++r) acc[i][j][r] = 0.f;

  const bf16* Abase = A + (size_t)tm * 128 * K;
  const bf16* Bbase = Bm + (size_t)tn * 128 * K;

  for (int k0 = 0; k0 < K; k0 += 64) {
#pragma unroll
    for (int it = 0; it < 4; ++it) {
      const int gidx = it * 256 + tid;
      const int row = gidx >> 3, c = gidx & 7;
      const int csw = c ^ (row & 7);  // pre-swizzled global source
      gload_lds16(Abase + (size_t)row * K + k0 + csw * 8,
                  As + (size_t)(it * 256 + wave * 64) * 8);
      gload_lds16(Bbase + (size_t)row * K + k0 + csw * 8,
                  Bs + (size_t)(it * 256 + wave * 64) * 8);
    }
    __syncthreads();
#pragma unroll
    for (int kc = 0; kc < 2; ++kc) {
      bf16x8 af[4], bfr[4];
#pragma unroll
      for (int i = 0; i < 4; ++i) {
        const int ra = wm + i * 16 + l15;
        af[i] = *(const bf16x8*)(As + ra * 64 + (((kc * 4 + l4) ^ (ra & 7)) * 8));
        const int rb = wn + i * 16 + l15;
        bfr[i] = *(const bf16x8*)(Bs + rb * 64 + (((kc * 4 + l4) ^ (rb & 7)) * 8));
      }
#pragma unroll
      for (int i = 0; i < 4; ++i)
#pragma unroll
        for (int j = 0; j < 4; ++j)
          acc[i][j] = __builtin_amdgcn_mfma_f32_16x16x32_bf16(af[i], bfr[j],
                                                              acc[i][j], 0, 0, 0);
    }
    __syncthreads();
  }

  if (mode == 0) {
#pragma unroll
    for (int i = 0; i < 4; ++i) {
      const int m0 = tm * 128 + wm + i * 16 + l4 * 4;
      const int b = m0 >> 11, s = m0 & (S_ - 1);
#pragma unroll
      for (int j = 0; j < 4; ++j) {
        const int n = tn * 128 + wn + j * 16 + l15;
        const int which = n >> 10;
        const int hn = n & 1023;
        const int h = hn >> 6, d = hn & 63;
        const f32x4 a = acc[i][j];
        if (which == 0) {
#pragma unroll
          for (int r = 0; r < 4; ++r)
            qd[((size_t)(b * H_ + h) * S_ + (s + r)) * D_ + d] =
                (bf16)(a[r] * 0.125f);
        } else if (which == 1) {
#pragma unroll
          for (int r = 0; r < 4; ++r)
            kd[((size_t)(b * H_ + h) * S_ + (s + r)) * D_ + d] = (bf16)a[r];
        } else {
          bf16x4 pv;
#pragma unroll
          for (int r = 0; r < 4; ++r) pv[r] = (bf16)a[r];
          *(bf16x4*)(vtd + ((size_t)(b * H_ + h) * D_ + d) * S_ + s) = pv;
        }
      }
    }
  } else {
#pragma unroll
    for (int i = 0; i < 4; ++i) {
      const int m0 = tm * 128 + wm + i * 16 + l4 * 4;
#pragma unroll
      for (int j = 0; j < 4; ++j) {
        const int n = tn * 128 + wn + j * 16 + l15;
#pragma unroll
        for (int r = 0; r < 4; ++r) outf[(size_t)(m0 + r) * N + n] = acc[i][j][r];
      }
    }
  }
}

// ---------------- mean of v over all S (for fully-masked rows) ----------------
__global__ __launch_bounds__(256) void meanv_kernel(const bf16* __restrict__ vt,
                                                    float* __restrict__ meanv) {
  __shared__ float part[256];
  const int bh = blockIdx.x;
  const int tid = threadIdx.x;
  const int d = tid & 63, seg = tid >> 6;
  const bf16* row = vt + ((size_t)bh * D_ + d) * S_ + seg * 512;
  float s = 0.f;
  for (int i = 0; i < 512; i += 8) {
    bf16x8 v = *(const bf16x8*)(row + i);
#pragma unroll
    for (int j = 0; j < 8; ++j) s += (float)v[j];
  }
  part[tid] = s;
  __syncthreads();
  if (tid < 64) {
    float t = part[tid] + part[64 + tid] + part[128 + tid] + part[192 + tid];
    meanv[(size_t)bh * D_ + tid] = t * (1.0f / (float)S_);
  }
}

// ---------------- flash attention: swapped QK^T 32x32, in-register softmax --
// Wave handles 32 q-rows (q = q0w + (lane&31)); keys tile = 32.
// S^T layout: col=lane&31=q, row=key=(reg&3)+8*(reg>>2)+4*(lane>>5).
// PV computed as O^T = V^T * P^T (A=V^T rows=d, B=P^T via permlane32_swap).
__device__ __forceinline__ int pk2(float a, float b) {
  union { bf16x2 h; int i; } u;
  u.h[0] = (bf16)a; u.h[1] = (bf16)b;
  return u.i;
}

__global__ __launch_bounds__(256) void attn_kernel(
    const bf16* __restrict__ q, const bf16* __restrict__ k,
    const bf16* __restrict__ vt, const float* __restrict__ meanv,
    const int* __restrict__ seq_lengths, const int* __restrict__ wlp,
    const int* __restrict__ wrp, bf16* __restrict__ attn_out) {
  const int tid = threadIdx.x, wave = tid >> 6, lane = tid & 63;
  const int l31 = lane & 31, l5 = lane >> 5;
  const int bid = blockIdx.x;
  const int bh = bid >> 4;  // 16 blocks of 128 q-rows per (b,h)
  const int g = bid & 15;
  const int b = bh >> 4, h = bh & 15;
  const int q0w = g * 128 + wave * 32;
  const int seq_len = seq_lengths[b];
  const int wl = wlp[0], wr = wrp[0];

  const bf16* qbase = q + (size_t)bh * S_ * D_;
  const bf16* kbase = k + (size_t)bh * S_ * D_;
  const bf16* vtb = vt + (size_t)bh * D_ * S_;

  // Q fragments (B-operand): col=l31=q-row, k-dim = d = dg*16 + l5*8 + j
  bf16x8 qa[4];
#pragma unroll
  for (int dg = 0; dg < 4; ++dg)
    qa[dg] = *(const bf16x8*)(qbase + (size_t)(q0w + l31) * D_ + dg * 16 + l5 * 8);

  const int hi_ = (wr >= 0) ? imin(q0w + 31 + wr, S_ - 1) : (S_ - 1);
  const int kv_end = imin(hi_ + 1, seq_len);
  const int lo_ = (wl >= 0) ? imax(0, q0w - wl) : 0;
  const int kv_begin = lo_ & ~31;

  f32x16 o0, o1;
#pragma unroll
  for (int r = 0; r < 16; ++r) { o0[r] = 0.f; o1[r] = 0.f; }
  float mrun = -1e30f, lrun = 0.f;

  for (int kt = kv_begin; kt < kv_end; kt += 32) {
    // ---- QK^T: S^T = K * Q^T  (4 chained mfma over d) ----
    f32x16 sf;
#pragma unroll
    for (int r = 0; r < 16; ++r) sf[r] = 0.f;
#pragma unroll
    for (int dg = 0; dg < 4; ++dg) {
      bf16x8 kb = *(const bf16x8*)(kbase + (size_t)(kt + l31) * D_ + dg * 16 + l5 * 8);
      sf = __builtin_amdgcn_mfma_f32_32x32x16_bf16(kb, qa[dg], sf, 0, 0, 0);
    }

    // ---- mask (interior fast path) + per-lane max ----
    bool allv = (kt + 31 < seq_len);
    if (wr >= 0) allv = allv && (kt + 31 <= q0w + wr);
    if (wl >= 0) allv = allv && (kt >= q0w + 31 - wl);

    float p[16];
    float tmax = -1e30f;
    if (allv) {
#pragma unroll
      for (int r = 0; r < 16; ++r) { p[r] = sf[r]; tmax = fmaxf(tmax, p[r]); }
    } else {
      const int qrow = q0w + l31;
#pragma unroll
      for (int r = 0; r < 16; ++r) {
        const int key = kt + (r & 3) + 8 * (r >> 2) + 4 * l5;
        bool valid = (key < seq_len);
        if (wr >= 0) valid = valid && (key <= qrow + wr);
        if (wl >= 0) valid = valid && (key >= qrow - wl);
        p[r] = valid ? sf[r] : -1e30f;
        tmax = fmaxf(tmax, p[r]);
      }
    }
    tmax = fmaxf(tmax, __shfl_xor(tmax, 32, 64));

    // ---- defer-max (T13): rescale only when max grows past threshold ----
    if (!__all(tmax <= mrun + 8.0f)) {
      const float mnew = fmaxf(mrun, tmax);
      const float corr = __expf(mrun - mnew);
      mrun = mnew;
      lrun *= corr;
#pragma unroll
      for (int r = 0; r < 16; ++r) { o0[r] *= corr; o1[r] *= corr; }
    }

    // ---- exp + row-sum ----
    float lsum = 0.f;
#pragma unroll
    for (int r = 0; r < 16; ++r) {
      const float pe = (p[r] <= -1e29f) ? 0.f : __expf(p[r] - mrun);
      p[r] = pe;
      lsum += pe;
    }
    lsum += __shfl_xor(lsum, 32, 64);
    lrun += lsum;

    // ---- P^T -> bf16 B-fragments via permlane32_swap (T12) ----
    bf16x8 pb[2];
#pragma unroll
    for (int kg = 0; kg < 2; ++kg) {
      const int w0 = pk2(p[kg * 8 + 0], p[kg * 8 + 1]);
      const int w1 = pk2(p[kg * 8 + 2], p[kg * 8 + 3]);
      const int w2 = pk2(p[kg * 8 + 4], p[kg * 8 + 5]);
      const int w3 = pk2(p[kg * 8 + 6], p[kg * 8 + 7]);
      auto r02 = __builtin_amdgcn_permlane32_swap(w0, w2, false, false);
      auto r13 = __builtin_amdgcn_permlane32_swap(w1, w3, false, false);
      union { int i[4]; bf16x8 v; } u;
      u.i[0] = r02[0]; u.i[1] = r13[0]; u.i[2] = r02[1]; u.i[3] = r13[1];
      pb[kg] = u.v;
    }

    // ---- PV: O^T += V^T * P^T ----
#pragma unroll
    for (int kg = 0; kg < 2; ++kg) {
      bf16x8 v0 = *(const bf16x8*)(vtb + (size_t)(l31) * S_ + kt + kg * 16 + l5 * 8);
      bf16x8 v1 = *(const bf16x8*)(vtb + (size_t)(32 + l31) * S_ + kt + kg * 16 + l5 * 8);
      o0 = __builtin_amdgcn_mfma_f32_32x32x16_bf16(v0, pb[kg], o0, 0, 0, 0);
      o1 = __builtin_amdgcn_mfma_f32_32x32x16_bf16(v1, pb[kg], o1, 0, 0, 0);
    }
  }

  // ---- epilogue ----
  const int qrow = q0w + l31;
  bf16* outp = attn_out + ((size_t)(b * S_ + qrow)) * E_ + h * 64;
  if (lrun > 0.f) {
    const float inv = 1.0f / lrun;
#pragma unroll
    for (int dg2 = 0; dg2 < 2; ++dg2) {
      const f32x16& o = dg2 ? o1 : o0;
#pragma unroll
      for (int rg = 0; rg < 4; ++rg) {
        const int d0 = dg2 * 32 + 8 * rg + 4 * l5;
        bf16x4 ov;
#pragma unroll
        for (int j = 0; j < 4; ++j) ov[j] = (bf16)(o[rg * 4 + j] * inv);
        *(bf16x4*)(outp + d0) = ov;
      }
    }
  } else {
    const float* mv = meanv + (size_t)bh * D_;
#pragma unroll
    for (int dg2 = 0; dg2 < 2; ++dg2)
#pragma unroll
      for (int rg = 0; rg < 4; ++rg) {
        const int d0 = dg2 * 32 + 8 * rg + 4 * l5;
        bf16x4 ov;
#pragma unroll
        for (int j = 0; j < 4; ++j) ov[j] = (bf16)mv[d0 + j];
        *(bf16x4*)(outp + d0) = ov;
      }
  }
}

// ---------------- launch ----------------
extern "C" void kernel_launch(void* const* d_in, const int* in_sizes, int n_in,
                              void* d_out, int out_size, void* d_ws, size_t ws_size,
                              hipStream_t stream) {
  const float* x = (const float*)d_in[0];
  const float* Wqkv = (const float*)d_in[1];
  const float* Wout = (const float*)d_in[2];
  const int* seq_lengths = (const int*)d_in[3];
  const int* wl = (const int*)d_in[4];
  const int* wr = (const int*)d_in[5];
  float* out = (float*)d_out;

  char* ws = (char*)d_ws;
  bf16* xb = (bf16*)ws;      ws += (size_t)8192 * 1024 * 2;
  bf16* wqkvb = (bf16*)ws;   ws += (size_t)3072 * 1024 * 2;
  bf16* woutb = (bf16*)ws;   ws += (size_t)1024 * 1024 * 2;
  bf16* qd = (bf16*)ws;      ws += (size_t)B_ * H_ * S_ * D_ * 2;
  bf16* kd = (bf16*)ws;      ws += (size_t)B_ * H_ * S_ * D_ * 2;
  bf16* vtd = (bf16*)ws;     ws += (size_t)B_ * H_ * S_ * D_ * 2;
  bf16* attn = (bf16*)ws;    ws += (size_t)8192 * 1024 * 2;
  float* meanv = (float*)ws; ws += (size_t)B_ * H_ * D_ * 4;

  f32_to_bf16_kernel<<<2048, 256, 0, stream>>>(x, xb, 8192 * 1024);
  f32_to_bf16_kernel<<<768, 256, 0, stream>>>(Wqkv, wqkvb, 3072 * 1024);
  f32_to_bf16_kernel<<<512, 256, 0, stream>>>(Wout, woutb, 1024 * 1024);

  gemm_nt<<<dim3(24, 64), 256, 0, stream>>>(xb, wqkvb, 8192, 3072, 1024, 0,
                                            qd, kd, vtd, nullptr);
  meanv_kernel<<<64, 256, 0, stream>>>(vtd, meanv);
  attn_kernel<<<1024, 256, 0, stream>>>(qd, kd, vtd, meanv, seq_lengths, wl, wr,
                                        attn);
  gemm_nt<<<dim3(8, 64), 256, 0, stream>>>(attn, woutb, 8192, 1024, 1024, 1,
                                           nullptr, nullptr, nullptr, out);
}

// Round 4
// 192.492 us; speedup vs baseline: 1.3402x; 1.0091x over previous
//
#include <hip/hip_runtime.h>

typedef __bf16 bf16;
typedef __attribute__((ext_vector_type(2))) __bf16 bf16x2;
typedef __attribute__((ext_vector_type(4))) __bf16 bf16x4;
typedef __attribute__((ext_vector_type(8))) __bf16 bf16x8;
typedef __attribute__((ext_vector_type(4))) float f32x4;
typedef __attribute__((ext_vector_type(16))) float f32x16;

#define B_ 4
#define S_ 2048
#define H_ 16
#define D_ 64
#define E_ 1024

__device__ __forceinline__ int imin(int a, int b) { return a < b ? a : b; }
__device__ __forceinline__ int imax(int a, int b) { return a > b ? a : b; }

__device__ __forceinline__ void gload_lds16(const void* g, void* l) {
  __builtin_amdgcn_global_load_lds(
      (const __attribute__((address_space(1))) void*)g,
      (__attribute__((address_space(3))) void*)l, 16, 0, 0);
}

// ---------------- f32 -> bf16 convert (8 elems/thread) ----------------
__global__ __launch_bounds__(256) void f32_to_bf16_kernel(
    const float* __restrict__ in, bf16* __restrict__ out, int n) {
  int i = (blockIdx.x * 256 + threadIdx.x) * 8;
  const int stride = gridDim.x * 256 * 8;
  for (; i < n; i += stride) {
    float4 v0 = *(const float4*)(in + i);
    float4 v1 = *(const float4*)(in + i + 4);
    bf16x8 o;
    o[0] = (bf16)v0.x; o[1] = (bf16)v0.y; o[2] = (bf16)v0.z; o[3] = (bf16)v0.w;
    o[4] = (bf16)v1.x; o[5] = (bf16)v1.y; o[6] = (bf16)v1.z; o[7] = (bf16)v1.w;
    *(bf16x8*)(out + i) = o;
  }
}

// ---------------- NT bf16 GEMM: C[m,n] = sum_k A[m,k]*B[n,k] ----------------
__global__ __launch_bounds__(256) void gemm_nt(
    const bf16* __restrict__ A, const bf16* __restrict__ Bm,
    int M, int N, int K, int mode,
    bf16* __restrict__ qd, bf16* __restrict__ kd, bf16* __restrict__ vtd,
    float* __restrict__ outf) {
  __shared__ __align__(16) bf16 As[128 * 64];
  __shared__ __align__(16) bf16 Bs[128 * 64];
  const int tid = threadIdx.x;
  const int wave = tid >> 6, lane = tid & 63;
  const int l15 = lane & 15, l4 = lane >> 4;
  const int tn = blockIdx.x, tm = blockIdx.y;
  const int wm = (wave >> 1) * 64, wn = (wave & 1) * 64;

  f32x4 acc[4][4];
#pragma unroll
  for (int i = 0; i < 4; ++i)
#pragma unroll
    for (int j = 0; j < 4; ++j)
#pragma unroll
      for (int r = 0; r < 4; ++r) acc[i][j][r] = 0.f;

  const bf16* Abase = A + (size_t)tm * 128 * K;
  const bf16* Bbase = Bm + (size_t)tn * 128 * K;

  for (int k0 = 0; k0 < K; k0 += 64) {
#pragma unroll
    for (int it = 0; it < 4; ++it) {
      const int gidx = it * 256 + tid;
      const int row = gidx >> 3, c = gidx & 7;
      const int csw = c ^ (row & 7);  // pre-swizzled global source
      gload_lds16(Abase + (size_t)row * K + k0 + csw * 8,
                  As + (size_t)(it * 256 + wave * 64) * 8);
      gload_lds16(Bbase + (size_t)row * K + k0 + csw * 8,
                  Bs + (size_t)(it * 256 + wave * 64) * 8);
    }
    __syncthreads();
#pragma unroll
    for (int kc = 0; kc < 2; ++kc) {
      bf16x8 af[4], bfr[4];
#pragma unroll
      for (int i = 0; i < 4; ++i) {
        const int ra = wm + i * 16 + l15;
        af[i] = *(const bf16x8*)(As + ra * 64 + (((kc * 4 + l4) ^ (ra & 7)) * 8));
        const int rb = wn + i * 16 + l15;
        bfr[i] = *(const bf16x8*)(Bs + rb * 64 + (((kc * 4 + l4) ^ (rb & 7)) * 8));
      }
#pragma unroll
      for (int i = 0; i < 4; ++i)
#pragma unroll
        for (int j = 0; j < 4; ++j)
          acc[i][j] = __builtin_amdgcn_mfma_f32_16x16x32_bf16(af[i], bfr[j],
                                                              acc[i][j], 0, 0, 0);
    }
    __syncthreads();
  }

  if (mode == 0) {
#pragma unroll
    for (int i = 0; i < 4; ++i) {
      const int m0 = tm * 128 + wm + i * 16 + l4 * 4;
      const int b = m0 >> 11, s = m0 & (S_ - 1);
#pragma unroll
      for (int j = 0; j < 4; ++j) {
        const int n = tn * 128 + wn + j * 16 + l15;
        const int which = n >> 10;
        const int hn = n & 1023;
        const int h = hn >> 6, d = hn & 63;
        const f32x4 a = acc[i][j];
        if (which == 0) {
#pragma unroll
          for (int r = 0; r < 4; ++r)
            qd[((size_t)(b * H_ + h) * S_ + (s + r)) * D_ + d] =
                (bf16)(a[r] * 0.125f);
        } else if (which == 1) {
#pragma unroll
          for (int r = 0; r < 4; ++r)
            kd[((size_t)(b * H_ + h) * S_ + (s + r)) * D_ + d] = (bf16)a[r];
        } else {
          bf16x4 pv;
#pragma unroll
          for (int r = 0; r < 4; ++r) pv[r] = (bf16)a[r];
          *(bf16x4*)(vtd + ((size_t)(b * H_ + h) * D_ + d) * S_ + s) = pv;
        }
      }
    }
  } else {
#pragma unroll
    for (int i = 0; i < 4; ++i) {
      const int m0 = tm * 128 + wm + i * 16 + l4 * 4;
#pragma unroll
      for (int j = 0; j < 4; ++j) {
        const int n = tn * 128 + wn + j * 16 + l15;
#pragma unroll
        for (int r = 0; r < 4; ++r) outf[(size_t)(m0 + r) * N + n] = acc[i][j][r];
      }
    }
  }
}

// ---------------- mean of v over all S (for fully-masked rows) ----------------
__global__ __launch_bounds__(256) void meanv_kernel(const bf16* __restrict__ vt,
                                                    float* __restrict__ meanv) {
  __shared__ float part[256];
  const int bh = blockIdx.x;
  const int tid = threadIdx.x;
  const int d = tid & 63, seg = tid >> 6;
  const bf16* row = vt + ((size_t)bh * D_ + d) * S_ + seg * 512;
  float s = 0.f;
  for (int i = 0; i < 512; i += 8) {
    bf16x8 v = *(const bf16x8*)(row + i);
#pragma unroll
    for (int j = 0; j < 8; ++j) s += (float)v[j];
  }
  part[tid] = s;
  __syncthreads();
  if (tid < 64) {
    float t = part[tid] + part[64 + tid] + part[128 + tid] + part[192 + tid];
    meanv[(size_t)bh * D_ + tid] = t * (1.0f / (float)S_);
  }
}

// ---------------- flash attention: swapped QK^T 32x32, split-kv x2 ----------
// Block = 2 waves over the SAME 32 q-rows; wave w takes kv tiles w, w+2, ...
// Partial (m,l,O) merged via LDS at the end. 1-deep K prefetch; V loads
// issued before softmax so latency hides under the exp chain.
__device__ __forceinline__ int pk2(float a, float b) {
  union { bf16x2 h; int i; } u;
  u.h[0] = (bf16)a; u.h[1] = (bf16)b;
  return u.i;
}

__global__ __launch_bounds__(128) void attn_kernel(
    const bf16* __restrict__ q, const bf16* __restrict__ k,
    const bf16* __restrict__ vt, const float* __restrict__ meanv,
    const int* __restrict__ seq_lengths, const int* __restrict__ wlp,
    const int* __restrict__ wrp, bf16* __restrict__ attn_out) {
  __shared__ float Lm[64], Ll[64];
  __shared__ float Lo[32][64];
  const int tid = threadIdx.x, wave = tid >> 6, lane = tid & 63;
  const int l31 = lane & 31, l5 = lane >> 5;
  // XCD-aware swizzle (T1): 4096 blocks, 8 XCDs, 512 per XCD chunk.
  const int bid0 = blockIdx.x;
  const int bid = (bid0 & 7) * 512 + (bid0 >> 3);
  const int bh = bid >> 6;  // 64 blocks of 32 q-rows per (b,h)
  const int g = bid & 63;
  const int b = bh >> 4, h = bh & 15;
  const int q0w = g * 32;
  const int seq_len = seq_lengths[b];
  const int wl = wlp[0], wr = wrp[0];

  const bf16* qbase = q + (size_t)bh * S_ * D_;
  const bf16* kbase = k + (size_t)bh * S_ * D_;
  const bf16* vtb = vt + (size_t)bh * D_ * S_;

  // Q fragments (B-operand): col=l31=q-row, k-dim = d = dg*16 + l5*8 + j
  bf16x8 qa[4];
#pragma unroll
  for (int dg = 0; dg < 4; ++dg)
    qa[dg] = *(const bf16x8*)(qbase + (size_t)(q0w + l31) * D_ + dg * 16 + l5 * 8);

  const int hi_ = (wr >= 0) ? imin(q0w + 31 + wr, S_ - 1) : (S_ - 1);
  const int kv_end = imin(hi_ + 1, seq_len);
  const int lo_ = (wl >= 0) ? imax(0, q0w - wl) : 0;
  const int kv_begin = lo_ & ~31;
  const int span = kv_end - kv_begin;
  const int nt = (span > 0) ? ((span + 31) >> 5) : 0;

  f32x16 o0, o1;
#pragma unroll
  for (int r = 0; r < 16; ++r) { o0[r] = 0.f; o1[r] = 0.f; }
  float mrun = -1e30f, lrun = 0.f;

  // prologue: prefetch this wave's first K tile (clamped, always in-bounds)
  int kt0 = kv_begin + wave * 32;
  if (wave >= nt) kt0 = kv_begin;
  bf16x8 kreg[4];
#pragma unroll
  for (int dg = 0; dg < 4; ++dg)
    kreg[dg] = *(const bf16x8*)(kbase + (size_t)(kt0 + l31) * D_ + dg * 16 + l5 * 8);

  for (int t = wave; t < nt; t += 2) {
    const int kt = kv_begin + t * 32;
    // ---- QK^T: S^T = K * Q^T ----
    f32x16 sf;
#pragma unroll
    for (int r = 0; r < 16; ++r) sf[r] = 0.f;
#pragma unroll
    for (int dg = 0; dg < 4; ++dg)
      sf = __builtin_amdgcn_mfma_f32_32x32x16_bf16(kreg[dg], qa[dg], sf, 0, 0, 0);

    // ---- issue V loads for current tile (latency hides under softmax) ----
    bf16x8 vreg[4];
#pragma unroll
    for (int kg = 0; kg < 2; ++kg) {
      vreg[kg * 2 + 0] = *(const bf16x8*)(vtb + (size_t)(l31) * S_ + kt + kg * 16 + l5 * 8);
      vreg[kg * 2 + 1] = *(const bf16x8*)(vtb + (size_t)(32 + l31) * S_ + kt + kg * 16 + l5 * 8);
    }
    // ---- prefetch next K tile (clamped dummy when out of range) ----
    int ktn = kv_begin + (t + 2) * 32;
    if (t + 2 >= nt) ktn = kv_begin;
#pragma unroll
    for (int dg = 0; dg < 4; ++dg)
      kreg[dg] = *(const bf16x8*)(kbase + (size_t)(ktn + l31) * D_ + dg * 16 + l5 * 8);

    // ---- mask (interior fast path) + per-lane max ----
    bool allv = (kt + 31 < seq_len);
    if (wr >= 0) allv = allv && (kt + 31 <= q0w + wr);
    if (wl >= 0) allv = allv && (kt >= q0w + 31 - wl);

    float p[16];
    float tmax = -1e30f;
    if (allv) {
#pragma unroll
      for (int r = 0; r < 16; ++r) { p[r] = sf[r]; tmax = fmaxf(tmax, p[r]); }
    } else {
      const int qrow = q0w + l31;
#pragma unroll
      for (int r = 0; r < 16; ++r) {
        const int key = kt + (r & 3) + 8 * (r >> 2) + 4 * l5;
        bool valid = (key < seq_len);
        if (wr >= 0) valid = valid && (key <= qrow + wr);
        if (wl >= 0) valid = valid && (key >= qrow - wl);
        p[r] = valid ? sf[r] : -1e30f;
        tmax = fmaxf(tmax, p[r]);
      }
    }
    tmax = fmaxf(tmax, __shfl_xor(tmax, 32, 64));

    // ---- defer-max (T13) ----
    if (!__all(tmax <= mrun + 8.0f)) {
      const float mnew = fmaxf(mrun, tmax);
      const float corr = __expf(mrun - mnew);
      mrun = mnew;
      lrun *= corr;
#pragma unroll
      for (int r = 0; r < 16; ++r) { o0[r] *= corr; o1[r] *= corr; }
    }

    // ---- exp + row-sum ----
    float lsum = 0.f;
#pragma unroll
    for (int r = 0; r < 16; ++r) {
      const float pe = (p[r] <= -1e29f) ? 0.f : __expf(p[r] - mrun);
      p[r] = pe;
      lsum += pe;
    }
    lsum += __shfl_xor(lsum, 32, 64);
    lrun += lsum;

    // ---- P^T -> bf16 B-fragments via permlane32_swap (T12) ----
    bf16x8 pb[2];
#pragma unroll
    for (int kg = 0; kg < 2; ++kg) {
      const int w0 = pk2(p[kg * 8 + 0], p[kg * 8 + 1]);
      const int w1 = pk2(p[kg * 8 + 2], p[kg * 8 + 3]);
      const int w2 = pk2(p[kg * 8 + 4], p[kg * 8 + 5]);
      const int w3 = pk2(p[kg * 8 + 6], p[kg * 8 + 7]);
      auto r02 = __builtin_amdgcn_permlane32_swap(w0, w2, false, false);
      auto r13 = __builtin_amdgcn_permlane32_swap(w1, w3, false, false);
      union { int i[4]; bf16x8 v; } u;
      u.i[0] = r02[0]; u.i[1] = r13[0]; u.i[2] = r02[1]; u.i[3] = r13[1];
      pb[kg] = u.v;
    }

    // ---- PV: O^T += V^T * P^T ----
#pragma unroll
    for (int kg = 0; kg < 2; ++kg) {
      o0 = __builtin_amdgcn_mfma_f32_32x32x16_bf16(vreg[kg * 2 + 0], pb[kg], o0, 0, 0, 0);
      o1 = __builtin_amdgcn_mfma_f32_32x32x16_bf16(vreg[kg * 2 + 1], pb[kg], o1, 0, 0, 0);
    }
  }

  // ---- merge the two waves' partials via LDS ----
  if (wave == 1) {
    Lm[lane] = mrun;
    Ll[lane] = lrun;
#pragma unroll
    for (int r = 0; r < 16; ++r) {
      Lo[r][lane] = o0[r];
      Lo[16 + r][lane] = o1[r];
    }
  }
  __syncthreads();
  if (wave == 1) return;

  const float m2 = Lm[lane], l2 = Ll[lane];
  const float ms = fmaxf(mrun, m2);
  const float w1 = __expf(mrun - ms), w2 = __expf(m2 - ms);
  const float ls = lrun * w1 + l2 * w2;
#pragma unroll
  for (int r = 0; r < 16; ++r) {
    o0[r] = o0[r] * w1 + Lo[r][lane] * w2;
    o1[r] = o1[r] * w1 + Lo[16 + r][lane] * w2;
  }

  // ---- epilogue ----
  const int qrow = q0w + l31;
  bf16* outp = attn_out + ((size_t)(b * S_ + qrow)) * E_ + h * 64;
  if (ls > 0.f) {
    const float inv = 1.0f / ls;
#pragma unroll
    for (int dg2 = 0; dg2 < 2; ++dg2) {
      const f32x16& o = dg2 ? o1 : o0;
#pragma unroll
      for (int rg = 0; rg < 4; ++rg) {
        const int d0 = dg2 * 32 + 8 * rg + 4 * l5;
        bf16x4 ov;
#pragma unroll
        for (int j = 0; j < 4; ++j) ov[j] = (bf16)(o[rg * 4 + j] * inv);
        *(bf16x4*)(outp + d0) = ov;
      }
    }
  } else {
    const float* mv = meanv + (size_t)bh * D_;
#pragma unroll
    for (int dg2 = 0; dg2 < 2; ++dg2)
#pragma unroll
      for (int rg = 0; rg < 4; ++rg) {
        const int d0 = dg2 * 32 + 8 * rg + 4 * l5;
        bf16x4 ov;
#pragma unroll
        for (int j = 0; j < 4; ++j) ov[j] = (bf16)mv[d0 + j];
        *(bf16x4*)(outp + d0) = ov;
      }
  }
}

// ---------------- launch ----------------
extern "C" void kernel_launch(void* const* d_in, const int* in_sizes, int n_in,
                              void* d_out, int out_size, void* d_ws, size_t ws_size,
                              hipStream_t stream) {
  const float* x = (const float*)d_in[0];
  const float* Wqkv = (const float*)d_in[1];
  const float* Wout = (const float*)d_in[2];
  const int* seq_lengths = (const int*)d_in[3];
  const int* wl = (const int*)d_in[4];
  const int* wr = (const int*)d_in[5];
  float* out = (float*)d_out;

  char* ws = (char*)d_ws;
  bf16* xb = (bf16*)ws;      ws += (size_t)8192 * 1024 * 2;
  bf16* wqkvb = (bf16*)ws;   ws += (size_t)3072 * 1024 * 2;
  bf16* woutb = (bf16*)ws;   ws += (size_t)1024 * 1024 * 2;
  bf16* qd = (bf16*)ws;      ws += (size_t)B_ * H_ * S_ * D_ * 2;
  bf16* kd = (bf16*)ws;      ws += (size_t)B_ * H_ * S_ * D_ * 2;
  bf16* vtd = (bf16*)ws;     ws += (size_t)B_ * H_ * S_ * D_ * 2;
  bf16* attn = (bf16*)ws;    ws += (size_t)8192 * 1024 * 2;
  float* meanv = (float*)ws; ws += (size_t)B_ * H_ * D_ * 4;

  f32_to_bf16_kernel<<<2048, 256, 0, stream>>>(x, xb, 8192 * 1024);
  f32_to_bf16_kernel<<<768, 256, 0, stream>>>(Wqkv, wqkvb, 3072 * 1024);
  f32_to_bf16_kernel<<<512, 256, 0, stream>>>(Wout, woutb, 1024 * 1024);

  gemm_nt<<<dim3(24, 64), 256, 0, stream>>>(xb, wqkvb, 8192, 3072, 1024, 0,
                                            qd, kd, vtd, nullptr);
  meanv_kernel<<<64, 256, 0, stream>>>(vtd, meanv);
  attn_kernel<<<4096, 128, 0, stream>>>(qd, kd, vtd, meanv, seq_lengths, wl, wr,
                                        attn);
  gemm_nt<<<dim3(8, 64), 256, 0, stream>>>(attn, woutb, 8192, 1024, 1024, 1,
                                           nullptr, nullptr, nullptr, out);
}

// Round 5
// 187.708 us; speedup vs baseline: 1.3744x; 1.0255x over previous
//
#include <hip/hip_runtime.h>

typedef __bf16 bf16;
typedef __attribute__((ext_vector_type(2))) __bf16 bf16x2;
typedef __attribute__((ext_vector_type(4))) __bf16 bf16x4;
typedef __attribute__((ext_vector_type(8))) __bf16 bf16x8;
typedef __attribute__((ext_vector_type(4))) float f32x4;
typedef __attribute__((ext_vector_type(16))) float f32x16;

#define B_ 4
#define S_ 2048
#define H_ 16
#define D_ 64
#define E_ 1024

#define BM 256
#define BN 128
#define BK 64

__device__ __forceinline__ int imin(int a, int b) { return a < b ? a : b; }
__device__ __forceinline__ int imax(int a, int b) { return a > b ? a : b; }

__device__ __forceinline__ void gload_lds16(const void* g, void* l) {
  __builtin_amdgcn_global_load_lds(
      (const __attribute__((address_space(1))) void*)g,
      (__attribute__((address_space(3))) void*)l, 16, 0, 0);
}

// ---------------- f32 -> bf16 convert (8 elems/thread) ----------------
__global__ __launch_bounds__(256) void f32_to_bf16_kernel(
    const float* __restrict__ in, bf16* __restrict__ out, int n) {
  int i = (blockIdx.x * 256 + threadIdx.x) * 8;
  const int stride = gridDim.x * 256 * 8;
  for (; i < n; i += stride) {
    float4 v0 = *(const float4*)(in + i);
    float4 v1 = *(const float4*)(in + i + 4);
    bf16x8 o;
    o[0] = (bf16)v0.x; o[1] = (bf16)v0.y; o[2] = (bf16)v0.z; o[3] = (bf16)v0.w;
    o[4] = (bf16)v1.x; o[5] = (bf16)v1.y; o[6] = (bf16)v1.z; o[7] = (bf16)v1.w;
    *(bf16x8*)(out + i) = o;
  }
}

// ------------- NT bf16 GEMM, 256x128 tile, 3-buf distance-2 pipeline -------
// C[m,n] = sum_k A[m,k]*B[n,k].  8 waves: wave m-chunk 64 rows, n-chunk 64 cols.
// LDS swizzle (T2, st_16x32): elem col ^= ((row>>2)&1)<<4, applied via
// inverse-swizzled global source (stage) + swizzled ds_read (both-sides).
// Counted vmcnt(6) at iter end (T4): tile t+1 landed, tile t+2 in flight.
__global__ __launch_bounds__(512, 1) void gemm_pipe(
    const bf16* __restrict__ A, const bf16* __restrict__ Bm,
    int M, int N, int K, int mode,
    bf16* __restrict__ qd, bf16* __restrict__ kd, bf16* __restrict__ vtd,
    float* __restrict__ outf) {
  __shared__ __align__(16) bf16 As[3][BM * BK];
  __shared__ __align__(16) bf16 Bs[3][BN * BK];
  const int tid = threadIdx.x;
  const int wave = tid >> 6, lane = tid & 63;
  const int l15 = lane & 15, l4 = lane >> 4;
  const int wm = (wave >> 1) * 64;   // 4 m-chunks
  const int wn = (wave & 1) * 64;    // 2 n-chunks

  // XCD-aware bijective swizzle (T1): consecutive swz ids share tm -> same L2
  const int nwg = gridDim.x * gridDim.y;
  const int fid = blockIdx.y * gridDim.x + blockIdx.x;
  const int chunk = nwg >> 3;  // nwg % 8 == 0 for both launches
  const int swz = (fid & 7) * chunk + (fid >> 3);
  const int tn = swz % gridDim.x;
  const int tm = swz / gridDim.x;

  const bf16* Abase = A + (size_t)tm * BM * K;
  const bf16* Bbase = Bm + (size_t)tn * BN * K;

  f32x4 acc[4][4];
#pragma unroll
  for (int i = 0; i < 4; ++i)
#pragma unroll
    for (int j = 0; j < 4; ++j)
#pragma unroll
      for (int r = 0; r < 4; ++r) acc[i][j][r] = 0.f;

  const int NT = K >> 6;  // = 16 for K=1024

  // stage helpers (lambdas): idx granule = 16B; inverse swizzle on global col
#define STAGE_A(sbuf, k0)                                                      \
  {                                                                            \
    _Pragma("unroll") for (int ld = 0; ld < 4; ++ld) {                         \
      const int idx = ld * 512 + tid;                                          \
      const int row = idx >> 3, g = idx & 7;                                   \
      const int gs = g ^ (((row >> 2) & 1) << 1);                              \
      gload_lds16(Abase + (size_t)row * K + (k0) + gs * 8,                     \
                  As[sbuf] + (ld * 512 + wave * 64) * 8);                      \
    }                                                                          \
  }
#define STAGE_B(sbuf, k0)                                                      \
  {                                                                            \
    _Pragma("unroll") for (int ld = 0; ld < 2; ++ld) {                         \
      const int idx = ld * 512 + tid;                                          \
      const int row = idx >> 3, g = idx & 7;                                   \
      const int gs = g ^ (((row >> 2) & 1) << 1);                              \
      gload_lds16(Bbase + (size_t)row * K + (k0) + gs * 8,                     \
                  Bs[sbuf] + (ld * 512 + wave * 64) * 8);                      \
    }                                                                          \
  }

  // prologue: stage tiles 0,1 into bufs 0,1
  STAGE_A(0, 0); STAGE_B(0, 0);
  STAGE_A(1, BK); STAGE_B(1, BK);
  asm volatile("s_waitcnt vmcnt(6)" ::: "memory");  // tile0 landed
  __builtin_amdgcn_s_barrier();

  int p = 0;
  for (int t = 0; t < NT; ++t) {
    const bf16* Ap = As[p];
    const bf16* Bp = Bs[p];
    const int sb = (p + 2 >= 3) ? p - 1 : p + 2;
    const int sk0 = ((t + 2 < NT) ? t + 2 : NT - 1) * BK;

    // ---- ds_read ks=0 frags ----
    bf16x8 a[4], bfr[4];
#pragma unroll
    for (int i = 0; i < 4; ++i) {
      const int ra = wm + i * 16 + l15;
      a[i] = *(const bf16x8*)(Ap + ra * 64 + ((l4 * 8) ^ (((ra >> 2) & 1) << 4)));
      const int rb = wn + i * 16 + l15;
      bfr[i] = *(const bf16x8*)(Bp + rb * 64 + ((l4 * 8) ^ (((rb >> 2) & 1) << 4)));
    }
    // ---- stage A of tile t+2 (4 loads) ----
    STAGE_A(sb, sk0);
    // ---- MFMA ks=0 ----
    __builtin_amdgcn_s_setprio(1);
#pragma unroll
    for (int i = 0; i < 4; ++i)
#pragma unroll
      for (int j = 0; j < 4; ++j)
        acc[i][j] = __builtin_amdgcn_mfma_f32_16x16x32_bf16(a[i], bfr[j],
                                                            acc[i][j], 0, 0, 0);
    __builtin_amdgcn_s_setprio(0);
    // ---- ds_read ks=1 frags ----
#pragma unroll
    for (int i = 0; i < 4; ++i) {
      const int ra = wm + i * 16 + l15;
      a[i] = *(const bf16x8*)(Ap + ra * 64 + ((32 + l4 * 8) ^ (((ra >> 2) & 1) << 4)));
      const int rb = wn + i * 16 + l15;
      bfr[i] = *(const bf16x8*)(Bp + rb * 64 + ((32 + l4 * 8) ^ (((rb >> 2) & 1) << 4)));
    }
    // ---- stage B of tile t+2 (2 loads) ----
    STAGE_B(sb, sk0);
    // ---- MFMA ks=1 ----
    __builtin_amdgcn_s_setprio(1);
#pragma unroll
    for (int i = 0; i < 4; ++i)
#pragma unroll
      for (int j = 0; j < 4; ++j)
        acc[i][j] = __builtin_amdgcn_mfma_f32_16x16x32_bf16(a[i], bfr[j],
                                                            acc[i][j], 0, 0, 0);
    __builtin_amdgcn_s_setprio(0);

    // ---- counted vmcnt: tile t+1 landed, tile t+2's 6 stay in flight ----
    asm volatile("s_waitcnt vmcnt(6)" ::: "memory");
    __builtin_amdgcn_s_barrier();
    p = (p + 1 >= 3) ? 0 : p + 1;
  }
#undef STAGE_A
#undef STAGE_B

  // ---- epilogue ----
  if (mode == 0) {
#pragma unroll
    for (int i = 0; i < 4; ++i) {
      const int m0 = tm * BM + wm + i * 16 + l4 * 4;
      const int b = m0 >> 11, s = m0 & (S_ - 1);
#pragma unroll
      for (int j = 0; j < 4; ++j) {
        const int n = tn * BN + wn + j * 16 + l15;
        const int which = n >> 10;
        const int hn = n & 1023;
        const int h = hn >> 6, d = hn & 63;
        const f32x4 av = acc[i][j];
        if (which == 0) {
#pragma unroll
          for (int r = 0; r < 4; ++r)
            qd[((size_t)(b * H_ + h) * S_ + (s + r)) * D_ + d] =
                (bf16)(av[r] * 0.125f);
        } else if (which == 1) {
#pragma unroll
          for (int r = 0; r < 4; ++r)
            kd[((size_t)(b * H_ + h) * S_ + (s + r)) * D_ + d] = (bf16)av[r];
        } else {
          bf16x4 pv;
#pragma unroll
          for (int r = 0; r < 4; ++r) pv[r] = (bf16)av[r];
          *(bf16x4*)(vtd + ((size_t)(b * H_ + h) * D_ + d) * S_ + s) = pv;
        }
      }
    }
  } else {
#pragma unroll
    for (int i = 0; i < 4; ++i) {
      const int m0 = tm * BM + wm + i * 16 + l4 * 4;
#pragma unroll
      for (int j = 0; j < 4; ++j) {
        const int n = tn * BN + wn + j * 16 + l15;
#pragma unroll
        for (int r = 0; r < 4; ++r) outf[(size_t)(m0 + r) * N + n] = acc[i][j][r];
      }
    }
  }
}

// ---------------- mean of v over all S (for fully-masked rows) ----------------
__global__ __launch_bounds__(256) void meanv_kernel(const bf16* __restrict__ vt,
                                                    float* __restrict__ meanv) {
  __shared__ float part[256];
  const int bh = blockIdx.x;
  const int tid = threadIdx.x;
  const int d = tid & 63, seg = tid >> 6;
  const bf16* row = vt + ((size_t)bh * D_ + d) * S_ + seg * 512;
  float s = 0.f;
  for (int i = 0; i < 512; i += 8) {
    bf16x8 v = *(const bf16x8*)(row + i);
#pragma unroll
    for (int j = 0; j < 8; ++j) s += (float)v[j];
  }
  part[tid] = s;
  __syncthreads();
  if (tid < 64) {
    float t = part[tid] + part[64 + tid] + part[128 + tid] + part[192 + tid];
    meanv[(size_t)bh * D_ + tid] = t * (1.0f / (float)S_);
  }
}

// ---------------- flash attention: swapped QK^T 32x32, split-kv x2 ----------
__device__ __forceinline__ int pk2(float a, float b) {
  union { bf16x2 h; int i; } u;
  u.h[0] = (bf16)a; u.h[1] = (bf16)b;
  return u.i;
}

__global__ __launch_bounds__(128) void attn_kernel(
    const bf16* __restrict__ q, const bf16* __restrict__ k,
    const bf16* __restrict__ vt, const float* __restrict__ meanv,
    const int* __restrict__ seq_lengths, const int* __restrict__ wlp,
    const int* __restrict__ wrp, bf16* __restrict__ attn_out) {
  __shared__ float Lm[64], Ll[64];
  __shared__ float Lo[32][64];
  const int tid = threadIdx.x, wave = tid >> 6, lane = tid & 63;
  const int l31 = lane & 31, l5 = lane >> 5;
  const int bid0 = blockIdx.x;
  const int bid = (bid0 & 7) * 512 + (bid0 >> 3);
  const int bh = bid >> 6;
  const int g = bid & 63;
  const int b = bh >> 4, h = bh & 15;
  const int q0w = g * 32;
  const int seq_len = seq_lengths[b];
  const int wl = wlp[0], wr = wrp[0];

  const bf16* qbase = q + (size_t)bh * S_ * D_;
  const bf16* kbase = k + (size_t)bh * S_ * D_;
  const bf16* vtb = vt + (size_t)bh * D_ * S_;

  bf16x8 qa[4];
#pragma unroll
  for (int dg = 0; dg < 4; ++dg)
    qa[dg] = *(const bf16x8*)(qbase + (size_t)(q0w + l31) * D_ + dg * 16 + l5 * 8);

  const int hi_ = (wr >= 0) ? imin(q0w + 31 + wr, S_ - 1) : (S_ - 1);
  const int kv_end = imin(hi_ + 1, seq_len);
  const int lo_ = (wl >= 0) ? imax(0, q0w - wl) : 0;
  const int kv_begin = lo_ & ~31;
  const int span = kv_end - kv_begin;
  const int nt = (span > 0) ? ((span + 31) >> 5) : 0;

  f32x16 o0, o1;
#pragma unroll
  for (int r = 0; r < 16; ++r) { o0[r] = 0.f; o1[r] = 0.f; }
  float mrun = -1e30f, lrun = 0.f;

  int kt0 = kv_begin + wave * 32;
  if (wave >= nt) kt0 = kv_begin;
  bf16x8 kreg[4];
#pragma unroll
  for (int dg = 0; dg < 4; ++dg)
    kreg[dg] = *(const bf16x8*)(kbase + (size_t)(kt0 + l31) * D_ + dg * 16 + l5 * 8);

  for (int t = wave; t < nt; t += 2) {
    const int kt = kv_begin + t * 32;
    f32x16 sf;
#pragma unroll
    for (int r = 0; r < 16; ++r) sf[r] = 0.f;
#pragma unroll
    for (int dg = 0; dg < 4; ++dg)
      sf = __builtin_amdgcn_mfma_f32_32x32x16_bf16(kreg[dg], qa[dg], sf, 0, 0, 0);

    bf16x8 vreg[4];
#pragma unroll
    for (int kg = 0; kg < 2; ++kg) {
      vreg[kg * 2 + 0] = *(const bf16x8*)(vtb + (size_t)(l31) * S_ + kt + kg * 16 + l5 * 8);
      vreg[kg * 2 + 1] = *(const bf16x8*)(vtb + (size_t)(32 + l31) * S_ + kt + kg * 16 + l5 * 8);
    }
    int ktn = kv_begin + (t + 2) * 32;
    if (t + 2 >= nt) ktn = kv_begin;
#pragma unroll
    for (int dg = 0; dg < 4; ++dg)
      kreg[dg] = *(const bf16x8*)(kbase + (size_t)(ktn + l31) * D_ + dg * 16 + l5 * 8);

    bool allv = (kt + 31 < seq_len);
    if (wr >= 0) allv = allv && (kt + 31 <= q0w + wr);
    if (wl >= 0) allv = allv && (kt >= q0w + 31 - wl);

    float p[16];
    float tmax = -1e30f;
    if (allv) {
#pragma unroll
      for (int r = 0; r < 16; ++r) { p[r] = sf[r]; tmax = fmaxf(tmax, p[r]); }
    } else {
      const int qrow = q0w + l31;
#pragma unroll
      for (int r = 0; r < 16; ++r) {
        const int key = kt + (r & 3) + 8 * (r >> 2) + 4 * l5;
        bool valid = (key < seq_len);
        if (wr >= 0) valid = valid && (key <= qrow + wr);
        if (wl >= 0) valid = valid && (key >= qrow - wl);
        p[r] = valid ? sf[r] : -1e30f;
        tmax = fmaxf(tmax, p[r]);
      }
    }
    tmax = fmaxf(tmax, __shfl_xor(tmax, 32, 64));

    if (!__all(tmax <= mrun + 8.0f)) {
      const float mnew = fmaxf(mrun, tmax);
      const float corr = __expf(mrun - mnew);
      mrun = mnew;
      lrun *= corr;
#pragma unroll
      for (int r = 0; r < 16; ++r) { o0[r] *= corr; o1[r] *= corr; }
    }

    float lsum = 0.f;
#pragma unroll
    for (int r = 0; r < 16; ++r) {
      const float pe = (p[r] <= -1e29f) ? 0.f : __expf(p[r] - mrun);
      p[r] = pe;
      lsum += pe;
    }
    lsum += __shfl_xor(lsum, 32, 64);
    lrun += lsum;

    bf16x8 pb[2];
#pragma unroll
    for (int kg = 0; kg < 2; ++kg) {
      const int w0 = pk2(p[kg * 8 + 0], p[kg * 8 + 1]);
      const int w1 = pk2(p[kg * 8 + 2], p[kg * 8 + 3]);
      const int w2 = pk2(p[kg * 8 + 4], p[kg * 8 + 5]);
      const int w3 = pk2(p[kg * 8 + 6], p[kg * 8 + 7]);
      auto r02 = __builtin_amdgcn_permlane32_swap(w0, w2, false, false);
      auto r13 = __builtin_amdgcn_permlane32_swap(w1, w3, false, false);
      union { int i[4]; bf16x8 v; } u;
      u.i[0] = r02[0]; u.i[1] = r13[0]; u.i[2] = r02[1]; u.i[3] = r13[1];
      pb[kg] = u.v;
    }

#pragma unroll
    for (int kg = 0; kg < 2; ++kg) {
      o0 = __builtin_amdgcn_mfma_f32_32x32x16_bf16(vreg[kg * 2 + 0], pb[kg], o0, 0, 0, 0);
      o1 = __builtin_amdgcn_mfma_f32_32x32x16_bf16(vreg[kg * 2 + 1], pb[kg], o1, 0, 0, 0);
    }
  }

  if (wave == 1) {
    Lm[lane] = mrun;
    Ll[lane] = lrun;
#pragma unroll
    for (int r = 0; r < 16; ++r) {
      Lo[r][lane] = o0[r];
      Lo[16 + r][lane] = o1[r];
    }
  }
  __syncthreads();
  if (wave == 1) return;

  const float m2 = Lm[lane], l2 = Ll[lane];
  const float ms = fmaxf(mrun, m2);
  const float w1 = __expf(mrun - ms), w2 = __expf(m2 - ms);
  const float ls = lrun * w1 + l2 * w2;
#pragma unroll
  for (int r = 0; r < 16; ++r) {
    o0[r] = o0[r] * w1 + Lo[r][lane] * w2;
    o1[r] = o1[r] * w1 + Lo[16 + r][lane] * w2;
  }

  const int qrow = q0w + l31;
  bf16* outp = attn_out + ((size_t)(b * S_ + qrow)) * E_ + h * 64;
  if (ls > 0.f) {
    const float inv = 1.0f / ls;
#pragma unroll
    for (int dg2 = 0; dg2 < 2; ++dg2) {
      const f32x16& o = dg2 ? o1 : o0;
#pragma unroll
      for (int rg = 0; rg < 4; ++rg) {
        const int d0 = dg2 * 32 + 8 * rg + 4 * l5;
        bf16x4 ov;
#pragma unroll
        for (int j = 0; j < 4; ++j) ov[j] = (bf16)(o[rg * 4 + j] * inv);
        *(bf16x4*)(outp + d0) = ov;
      }
    }
  } else {
    const float* mv = meanv + (size_t)bh * D_;
#pragma unroll
    for (int dg2 = 0; dg2 < 2; ++dg2)
#pragma unroll
      for (int rg = 0; rg < 4; ++rg) {
        const int d0 = dg2 * 32 + 8 * rg + 4 * l5;
        bf16x4 ov;
#pragma unroll
        for (int j = 0; j < 4; ++j) ov[j] = (bf16)mv[d0 + j];
        *(bf16x4*)(outp + d0) = ov;
      }
  }
}

// ---------------- launch ----------------
extern "C" void kernel_launch(void* const* d_in, const int* in_sizes, int n_in,
                              void* d_out, int out_size, void* d_ws, size_t ws_size,
                              hipStream_t stream) {
  const float* x = (const float*)d_in[0];
  const float* Wqkv = (const float*)d_in[1];
  const float* Wout = (const float*)d_in[2];
  const int* seq_lengths = (const int*)d_in[3];
  const int* wl = (const int*)d_in[4];
  const int* wr = (const int*)d_in[5];
  float* out = (float*)d_out;

  char* ws = (char*)d_ws;
  bf16* xb = (bf16*)ws;      ws += (size_t)8192 * 1024 * 2;
  bf16* wqkvb = (bf16*)ws;   ws += (size_t)3072 * 1024 * 2;
  bf16* woutb = (bf16*)ws;   ws += (size_t)1024 * 1024 * 2;
  bf16* qd = (bf16*)ws;      ws += (size_t)B_ * H_ * S_ * D_ * 2;
  bf16* kd = (bf16*)ws;      ws += (size_t)B_ * H_ * S_ * D_ * 2;
  bf16* vtd = (bf16*)ws;     ws += (size_t)B_ * H_ * S_ * D_ * 2;
  bf16* attn = (bf16*)ws;    ws += (size_t)8192 * 1024 * 2;
  float* meanv = (float*)ws; ws += (size_t)B_ * H_ * D_ * 4;

  f32_to_bf16_kernel<<<2048, 256, 0, stream>>>(x, xb, 8192 * 1024);
  f32_to_bf16_kernel<<<768, 256, 0, stream>>>(Wqkv, wqkvb, 3072 * 1024);
  f32_to_bf16_kernel<<<512, 256, 0, stream>>>(Wout, woutb, 1024 * 1024);

  gemm_pipe<<<dim3(24, 32), 512, 0, stream>>>(xb, wqkvb, 8192, 3072, 1024, 0,
                                              qd, kd, vtd, nullptr);
  meanv_kernel<<<64, 256, 0, stream>>>(vtd, meanv);
  attn_kernel<<<4096, 128, 0, stream>>>(qd, kd, vtd, meanv, seq_lengths, wl, wr,
                                        attn);
  gemm_pipe<<<dim3(8, 32), 512, 0, stream>>>(attn, woutb, 8192, 1024, 1024, 1,
                                             nullptr, nullptr, nullptr, out);
}

// Round 7
// 177.300 us; speedup vs baseline: 1.4550x; 1.0587x over previous
//
#include <hip/hip_runtime.h>

typedef __bf16 bf16;
typedef __attribute__((ext_vector_type(2))) __bf16 bf16x2;
typedef __attribute__((ext_vector_type(4))) __bf16 bf16x4;
typedef __attribute__((ext_vector_type(8))) __bf16 bf16x8;
typedef __attribute__((ext_vector_type(4))) float f32x4;
typedef __attribute__((ext_vector_type(16))) float f32x16;

#define B_ 4
#define S_ 2048
#define H_ 16
#define D_ 64
#define E_ 1024

#define BM 256
#define BN 128
#define BK 64

__device__ __forceinline__ int imin(int a, int b) { return a < b ? a : b; }
__device__ __forceinline__ int imax(int a, int b) { return a > b ? a : b; }

__device__ __forceinline__ void gload_lds16(const void* g, void* l) {
  __builtin_amdgcn_global_load_lds(
      (const __attribute__((address_space(1))) void*)g,
      (__attribute__((address_space(3))) void*)l, 16, 0, 0);
}

// ---------------- f32 -> bf16 convert (8 elems/thread) ----------------
__global__ __launch_bounds__(256) void f32_to_bf16_kernel(
    const float* __restrict__ in, bf16* __restrict__ out, int n) {
  int i = (blockIdx.x * 256 + threadIdx.x) * 8;
  const int stride = gridDim.x * 256 * 8;
  for (; i < n; i += stride) {
    float4 v0 = *(const float4*)(in + i);
    float4 v1 = *(const float4*)(in + i + 4);
    bf16x8 o;
    o[0] = (bf16)v0.x; o[1] = (bf16)v0.y; o[2] = (bf16)v0.z; o[3] = (bf16)v0.w;
    o[4] = (bf16)v1.x; o[5] = (bf16)v1.y; o[6] = (bf16)v1.z; o[7] = (bf16)v1.w;
    *(bf16x8*)(out + i) = o;
  }
}

// ------------- NT bf16 GEMM, 256x128 tile, 3-buf distance-2 pipeline -------
__global__ __launch_bounds__(512, 1) void gemm_pipe(
    const bf16* __restrict__ A, const bf16* __restrict__ Bm,
    int M, int N, int K, int mode,
    bf16* __restrict__ qd, bf16* __restrict__ kd, bf16* __restrict__ vtd,
    float* __restrict__ outf) {
  __shared__ __align__(16) bf16 As[3][BM * BK];
  __shared__ __align__(16) bf16 Bs[3][BN * BK];
  const int tid = threadIdx.x;
  const int wave = tid >> 6, lane = tid & 63;
  const int l15 = lane & 15, l4 = lane >> 4;
  const int wm = (wave >> 1) * 64;
  const int wn = (wave & 1) * 64;

  const int nwg = gridDim.x * gridDim.y;
  const int fid = blockIdx.y * gridDim.x + blockIdx.x;
  const int chunk = nwg >> 3;
  const int swz = (fid & 7) * chunk + (fid >> 3);
  const int tn = swz % gridDim.x;
  const int tm = swz / gridDim.x;

  const bf16* Abase = A + (size_t)tm * BM * K;
  const bf16* Bbase = Bm + (size_t)tn * BN * K;

  f32x4 acc[4][4];
#pragma unroll
  for (int i = 0; i < 4; ++i)
#pragma unroll
    for (int j = 0; j < 4; ++j)
#pragma unroll
      for (int r = 0; r < 4; ++r) acc[i][j][r] = 0.f;

  const int NT = K >> 6;

#define STAGE_A(sbuf, k0)                                                      \
  {                                                                            \
    _Pragma("unroll") for (int ld = 0; ld < 4; ++ld) {                         \
      const int idx = ld * 512 + tid;                                          \
      const int row = idx >> 3, g = idx & 7;                                   \
      const int gs = g ^ (((row >> 2) & 1) << 1);                              \
      gload_lds16(Abase + (size_t)row * K + (k0) + gs * 8,                     \
                  As[sbuf] + (ld * 512 + wave * 64) * 8);                      \
    }                                                                          \
  }
#define STAGE_B(sbuf, k0)                                                      \
  {                                                                            \
    _Pragma("unroll") for (int ld = 0; ld < 2; ++ld) {                         \
      const int idx = ld * 512 + tid;                                          \
      const int row = idx >> 3, g = idx & 7;                                   \
      const int gs = g ^ (((row >> 2) & 1) << 1);                              \
      gload_lds16(Bbase + (size_t)row * K + (k0) + gs * 8,                     \
                  Bs[sbuf] + (ld * 512 + wave * 64) * 8);                      \
    }                                                                          \
  }

  STAGE_A(0, 0); STAGE_B(0, 0);
  STAGE_A(1, BK); STAGE_B(1, BK);
  asm volatile("s_waitcnt vmcnt(6)" ::: "memory");
  __builtin_amdgcn_s_barrier();

  int p = 0;
  for (int t = 0; t < NT; ++t) {
    const bf16* Ap = As[p];
    const bf16* Bp = Bs[p];
    const int sb = (p + 2 >= 3) ? p - 1 : p + 2;
    const int sk0 = ((t + 2 < NT) ? t + 2 : NT - 1) * BK;

    bf16x8 a[4], bfr[4];
#pragma unroll
    for (int i = 0; i < 4; ++i) {
      const int ra = wm + i * 16 + l15;
      a[i] = *(const bf16x8*)(Ap + ra * 64 + ((l4 * 8) ^ (((ra >> 2) & 1) << 4)));
      const int rb = wn + i * 16 + l15;
      bfr[i] = *(const bf16x8*)(Bp + rb * 64 + ((l4 * 8) ^ (((rb >> 2) & 1) << 4)));
    }
    STAGE_A(sb, sk0);
    __builtin_amdgcn_s_setprio(1);
#pragma unroll
    for (int i = 0; i < 4; ++i)
#pragma unroll
      for (int j = 0; j < 4; ++j)
        acc[i][j] = __builtin_amdgcn_mfma_f32_16x16x32_bf16(a[i], bfr[j],
                                                            acc[i][j], 0, 0, 0);
    __builtin_amdgcn_s_setprio(0);
#pragma unroll
    for (int i = 0; i < 4; ++i) {
      const int ra = wm + i * 16 + l15;
      a[i] = *(const bf16x8*)(Ap + ra * 64 + ((32 + l4 * 8) ^ (((ra >> 2) & 1) << 4)));
      const int rb = wn + i * 16 + l15;
      bfr[i] = *(const bf16x8*)(Bp + rb * 64 + ((32 + l4 * 8) ^ (((rb >> 2) & 1) << 4)));
    }
    STAGE_B(sb, sk0);
    __builtin_amdgcn_s_setprio(1);
#pragma unroll
    for (int i = 0; i < 4; ++i)
#pragma unroll
      for (int j = 0; j < 4; ++j)
        acc[i][j] = __builtin_amdgcn_mfma_f32_16x16x32_bf16(a[i], bfr[j],
                                                            acc[i][j], 0, 0, 0);
    __builtin_amdgcn_s_setprio(0);

    asm volatile("s_waitcnt vmcnt(6)" ::: "memory");
    __builtin_amdgcn_s_barrier();
    p = (p + 1 >= 3) ? 0 : p + 1;
  }
#undef STAGE_A
#undef STAGE_B

  if (mode == 0) {
#pragma unroll
    for (int i = 0; i < 4; ++i) {
      const int m0 = tm * BM + wm + i * 16 + l4 * 4;
      const int b = m0 >> 11, s = m0 & (S_ - 1);
#pragma unroll
      for (int j = 0; j < 4; ++j) {
        const int n = tn * BN + wn + j * 16 + l15;
        const int which = n >> 10;
        const int hn = n & 1023;
        const int h = hn >> 6, d = hn & 63;
        const f32x4 av = acc[i][j];
        if (which == 0) {
#pragma unroll
          for (int r = 0; r < 4; ++r)
            qd[((size_t)(b * H_ + h) * S_ + (s + r)) * D_ + d] =
                (bf16)(av[r] * 0.125f);
        } else if (which == 1) {
#pragma unroll
          for (int r = 0; r < 4; ++r)
            kd[((size_t)(b * H_ + h) * S_ + (s + r)) * D_ + d] = (bf16)av[r];
        } else {
          bf16x4 pv;
#pragma unroll
          for (int r = 0; r < 4; ++r) pv[r] = (bf16)av[r];
          *(bf16x4*)(vtd + ((size_t)(b * H_ + h) * D_ + d) * S_ + s) = pv;
        }
      }
    }
  } else {
#pragma unroll
    for (int i = 0; i < 4; ++i) {
      const int m0 = tm * BM + wm + i * 16 + l4 * 4;
#pragma unroll
      for (int j = 0; j < 4; ++j) {
        const int n = tn * BN + wn + j * 16 + l15;
#pragma unroll
        for (int r = 0; r < 4; ++r) outf[(size_t)(m0 + r) * N + n] = acc[i][j][r];
      }
    }
  }
}

// ---------------- mean of v over all S (for fully-masked rows) ----------------
__global__ __launch_bounds__(256) void meanv_kernel(const bf16* __restrict__ vt,
                                                    float* __restrict__ meanv) {
  __shared__ float part[256];
  const int bh = blockIdx.x;
  const int tid = threadIdx.x;
  const int d = tid & 63, seg = tid >> 6;
  const bf16* row = vt + ((size_t)bh * D_ + d) * S_ + seg * 512;
  float s = 0.f;
  for (int i = 0; i < 512; i += 8) {
    bf16x8 v = *(const bf16x8*)(row + i);
#pragma unroll
    for (int j = 0; j < 8; ++j) s += (float)v[j];
  }
  part[tid] = s;
  __syncthreads();
  if (tid < 64) {
    float t = part[tid] + part[64 + tid] + part[128 + tid] + part[192 + tid];
    meanv[(size_t)bh * D_ + tid] = t * (1.0f / (float)S_);
  }
}

// -------- flash attention (m214-style): 4 waves x 32 q-rows, KVBLK=64 LDS --
// Block covers 128 q-rows; K tile [64 kv][64 d] and V^T tile [64 d][64 kv]
// staged to LDS once per block (global_load_lds, 3-bit XOR swizzle, dbuf).
// Swapped QK^T (mfma(K,Q)) keeps softmax fully in-register per lane.
__device__ __forceinline__ int pk2(float a, float b) {
  union { bf16x2 h; int i; } u;
  u.h[0] = (bf16)a; u.h[1] = (bf16)b;
  return u.i;
}

__global__ __launch_bounds__(256) void attn_kernel(
    const bf16* __restrict__ q, const bf16* __restrict__ k,
    const bf16* __restrict__ vt, const float* __restrict__ meanv,
    const int* __restrict__ seq_lengths, const int* __restrict__ wlp,
    const int* __restrict__ wrp, bf16* __restrict__ attn_out) {
  __shared__ __align__(16) bf16 Ks[2][64 * 64];
  __shared__ __align__(16) bf16 Vs[2][64 * 64];
  const int tid = threadIdx.x, wave = tid >> 6, lane = tid & 63;
  const int l31 = lane & 31, l5 = lane >> 5;
  // XCD swizzle (T1): 1024 blocks, 8 XCDs -> 128-chunks
  const int bid0 = blockIdx.x;
  const int bid = (bid0 & 7) * 128 + (bid0 >> 3);
  const int bh = bid >> 4;  // 16 blocks of 128 q-rows per (b,h)
  const int g = bid & 15;
  const int b = bh >> 4, h = bh & 15;
  const int q0b = g * 128;
  const int q0w = q0b + wave * 32;
  const int seq_len = seq_lengths[b];
  const int wl = wlp[0], wr = wrp[0];

  const bf16* qbase = q + (size_t)bh * S_ * D_;
  const bf16* kbase = k + (size_t)bh * S_ * D_;
  const bf16* vtb = vt + (size_t)bh * D_ * S_;

  // Q fragments (B-operand): col=l31=q-row, k-dim d = dg*16 + l5*8 + j
  bf16x8 qa[4];
#pragma unroll
  for (int dg = 0; dg < 4; ++dg)
    qa[dg] = *(const bf16x8*)(qbase + (size_t)(q0w + l31) * D_ + dg * 16 + l5 * 8);

  // block-level kv range (uniform across waves)
  const int hi_blk = (wr >= 0) ? imin(q0b + 127 + wr, S_ - 1) : (S_ - 1);
  const int end_blk = imin(hi_blk + 1, seq_len);
  const int lo_blk = (wl >= 0) ? imax(0, q0b - wl) : 0;
  const int beg_blk = lo_blk & ~63;
  const int ntb = (end_blk > beg_blk) ? ((end_blk - beg_blk + 63) >> 6) : 0;

  // wave-level compute range
  const int w_hi = (wr >= 0) ? (q0w + 31 + wr) : (S_ - 1);
  const int w_end = imin(w_hi + 1, seq_len);
  const int w_lo = (wl >= 0) ? imax(0, q0w - wl) : 0;

  f32x16 o0, o1;
#pragma unroll
  for (int r = 0; r < 16; ++r) { o0[r] = 0.f; o1[r] = 0.f; }
  float mrun = -1e30f, lrun = 0.f;

  // stage: 256 thr x (2 K granules + 2 V granules) of 16B; source col-swizzled
#define STAGE(bufb, kt0)                                                       \
  {                                                                            \
    _Pragma("unroll") for (int ld = 0; ld < 2; ++ld) {                         \
      const int idx = ld * 256 + tid;                                          \
      const int row = idx >> 3, gg = idx & 7;                                  \
      const int gs = gg ^ (row & 7);                                           \
      const int krow = imin((kt0) + row, S_ - 1);                              \
      gload_lds16(kbase + (size_t)krow * 64 + gs * 8, Ks[bufb] + idx * 8);     \
      const int vcol = imin((kt0) + gs * 8, S_ - 8);                           \
      gload_lds16(vtb + (size_t)row * S_ + vcol, Vs[bufb] + idx * 8);          \
    }                                                                          \
  }
#define LDS_K(bufb, row, gran)                                                 \
  (*(const bf16x8*)((const char*)(Ks[bufb]) + (row) * 128 +                    \
                    (((gran) ^ ((row) & 7)) << 4)))
#define LDS_V(bufb, row, gran)                                                 \
  (*(const bf16x8*)((const char*)(Vs[bufb]) + (row) * 128 +                    \
                    (((gran) ^ ((row) & 7)) << 4)))

  if (ntb > 0) STAGE(0, beg_blk);
  __syncthreads();

  for (int t = 0; t < ntb; ++t) {
    const int kt = beg_blk + t * 64;
    if (t + 1 < ntb) STAGE((t + 1) & 1, kt + 64);

    const bool active = (kt < w_end) && (kt + 63 >= w_lo);
    if (active) {
      const int bufb = t & 1;
      // ---- QK^T: S^T = K * Q^T, two kv-halves ----
      f32x16 sf0, sf1;
#pragma unroll
      for (int r = 0; r < 16; ++r) { sf0[r] = 0.f; sf1[r] = 0.f; }
#pragma unroll
      for (int dg = 0; dg < 4; ++dg) {
        bf16x8 kb0 = LDS_K(bufb, l31, dg * 2 + l5);
        bf16x8 kb1 = LDS_K(bufb, 32 + l31, dg * 2 + l5);
        sf0 = __builtin_amdgcn_mfma_f32_32x32x16_bf16(kb0, qa[dg], sf0, 0, 0, 0);
        sf1 = __builtin_amdgcn_mfma_f32_32x32x16_bf16(kb1, qa[dg], sf1, 0, 0, 0);
      }

      // ---- mask (interior fast path) ----
      bool allv = (kt + 63 < seq_len);
      if (wr >= 0) allv = allv && (kt + 63 <= q0w + wr);
      if (wl >= 0) allv = allv && (kt >= q0w + 31 - wl);
      if (!allv) {
        const int qrow = q0w + l31;
#pragma unroll
        for (int hh = 0; hh < 2; ++hh)
#pragma unroll
          for (int r = 0; r < 16; ++r) {
            const int key = kt + hh * 32 + (r & 3) + 8 * (r >> 2) + 4 * l5;
            bool valid = (key < seq_len);
            if (wr >= 0) valid = valid && (key <= qrow + wr);
            if (wl >= 0) valid = valid && (key >= qrow - wl);
            if (hh == 0) sf0[r] = valid ? sf0[r] : -1e30f;
            else sf1[r] = valid ? sf1[r] : -1e30f;
          }
      }
      float tmax = -1e30f;
#pragma unroll
      for (int r = 0; r < 16; ++r) {
        tmax = fmaxf(tmax, sf0[r]);
        tmax = fmaxf(tmax, sf1[r]);
      }
      tmax = fmaxf(tmax, __shfl_xor(tmax, 32, 64));

      // ---- defer-max (T13) ----
      if (!__all(tmax <= mrun + 8.0f)) {
        const float mnew = fmaxf(mrun, tmax);
        const float corr = __expf(mrun - mnew);
        mrun = mnew;
        lrun *= corr;
#pragma unroll
        for (int r = 0; r < 16; ++r) { o0[r] *= corr; o1[r] *= corr; }
      }

      // ---- exp + row-sum (in place) ----
      float lsum = 0.f;
#pragma unroll
      for (int r = 0; r < 16; ++r) {
        const float e0 = (sf0[r] <= -1e29f) ? 0.f : __expf(sf0[r] - mrun);
        const float e1 = (sf1[r] <= -1e29f) ? 0.f : __expf(sf1[r] - mrun);
        sf0[r] = e0; sf1[r] = e1;
        lsum += e0 + e1;
      }
      lsum += __shfl_xor(lsum, 32, 64);
      lrun += lsum;

      // ---- P^T -> bf16 B-fragments (T12) ----
      bf16x8 pb[4];
#pragma unroll
      for (int kg = 0; kg < 4; ++kg) {
        const int base = (kg & 1) * 8;
        float p0, p1, p2, p3, p4, p5, p6, p7;
        if (kg < 2) {
          p0 = sf0[base + 0]; p1 = sf0[base + 1]; p2 = sf0[base + 2];
          p3 = sf0[base + 3]; p4 = sf0[base + 4]; p5 = sf0[base + 5];
          p6 = sf0[base + 6]; p7 = sf0[base + 7];
        } else {
          p0 = sf1[base + 0]; p1 = sf1[base + 1]; p2 = sf1[base + 2];
          p3 = sf1[base + 3]; p4 = sf1[base + 4]; p5 = sf1[base + 5];
          p6 = sf1[base + 6]; p7 = sf1[base + 7];
        }
        const int w0 = pk2(p0, p1);
        const int w1 = pk2(p2, p3);
        const int w2 = pk2(p4, p5);
        const int w3 = pk2(p6, p7);
        auto r02 = __builtin_amdgcn_permlane32_swap(w0, w2, false, false);
        auto r13 = __builtin_amdgcn_permlane32_swap(w1, w3, false, false);
        union { int i[4]; bf16x8 v; } u;
        u.i[0] = r02[0]; u.i[1] = r13[0]; u.i[2] = r02[1]; u.i[3] = r13[1];
        pb[kg] = u.v;
      }

      // ---- PV: O^T += V^T * P^T ----
#pragma unroll
      for (int kg = 0; kg < 4; ++kg) {
        bf16x8 va0 = LDS_V(bufb, l31, kg * 2 + l5);
        bf16x8 va1 = LDS_V(bufb, 32 + l31, kg * 2 + l5);
        o0 = __builtin_amdgcn_mfma_f32_32x32x16_bf16(va0, pb[kg], o0, 0, 0, 0);
        o1 = __builtin_amdgcn_mfma_f32_32x32x16_bf16(va1, pb[kg], o1, 0, 0, 0);
      }
    }
    __syncthreads();
  }
#undef STAGE
#undef LDS_K
#undef LDS_V

  // ---- epilogue ----
  const int qrow = q0w + l31;
  bf16* outp = attn_out + ((size_t)(b * S_ + qrow)) * E_ + h * 64;
  if (lrun > 0.f) {
    const float inv = 1.0f / lrun;
#pragma unroll
    for (int dg2 = 0; dg2 < 2; ++dg2) {
      const f32x16& o = dg2 ? o1 : o0;
#pragma unroll
      for (int rg = 0; rg < 4; ++rg) {
        const int d0 = dg2 * 32 + 8 * rg + 4 * l5;
        bf16x4 ov;
#pragma unroll
        for (int j = 0; j < 4; ++j) ov[j] = (bf16)(o[rg * 4 + j] * inv);
        *(bf16x4*)(outp + d0) = ov;
      }
    }
  } else {
    const float* mv = meanv + (size_t)bh * D_;
#pragma unroll
    for (int dg2 = 0; dg2 < 2; ++dg2)
#pragma unroll
      for (int rg = 0; rg < 4; ++rg) {
        const int d0 = dg2 * 32 + 8 * rg + 4 * l5;
        bf16x4 ov;
#pragma unroll
        for (int j = 0; j < 4; ++j) ov[j] = (bf16)mv[d0 + j];
        *(bf16x4*)(outp + d0) = ov;
      }
  }
}

// ---------------- launch ----------------
extern "C" void kernel_launch(void* const* d_in, const int* in_sizes, int n_in,
                              void* d_out, int out_size, void* d_ws, size_t ws_size,
                              hipStream_t stream) {
  const float* x = (const float*)d_in[0];
  const float* Wqkv = (const float*)d_in[1];
  const float* Wout = (const float*)d_in[2];
  const int* seq_lengths = (const int*)d_in[3];
  const int* wl = (const int*)d_in[4];
  const int* wr = (const int*)d_in[5];
  float* out = (float*)d_out;

  char* ws = (char*)d_ws;
  bf16* xb = (bf16*)ws;      ws += (size_t)8192 * 1024 * 2;
  bf16* wqkvb = (bf16*)ws;   ws += (size_t)3072 * 1024 * 2;
  bf16* woutb = (bf16*)ws;   ws += (size_t)1024 * 1024 * 2;
  bf16* qd = (bf16*)ws;      ws += (size_t)B_ * H_ * S_ * D_ * 2;
  bf16* kd = (bf16*)ws;      ws += (size_t)B_ * H_ * S_ * D_ * 2;
  bf16* vtd = (bf16*)ws;     ws += (size_t)B_ * H_ * S_ * D_ * 2;
  bf16* attn = (bf16*)ws;    ws += (size_t)8192 * 1024 * 2;
  float* meanv = (float*)ws; ws += (size_t)B_ * H_ * D_ * 4;

  f32_to_bf16_kernel<<<2048, 256, 0, stream>>>(x, xb, 8192 * 1024);
  f32_to_bf16_kernel<<<768, 256, 0, stream>>>(Wqkv, wqkvb, 3072 * 1024);
  f32_to_bf16_kernel<<<512, 256, 0, stream>>>(Wout, woutb, 1024 * 1024);

  gemm_pipe<<<dim3(24, 32), 512, 0, stream>>>(xb, wqkvb, 8192, 3072, 1024, 0,
                                              qd, kd, vtd, nullptr);
  meanv_kernel<<<64, 256, 0, stream>>>(vtd, meanv);
  attn_kernel<<<1024, 256, 0, stream>>>(qd, kd, vtd, meanv, seq_lengths, wl, wr,
                                        attn);
  gemm_pipe<<<dim3(8, 32), 512, 0, stream>>>(attn, woutb, 8192, 1024, 1024, 1,
                                             nullptr, nullptr, nullptr, out);
}